// Round 5
// baseline (81.751 us; speedup 1.0000x reference)
//
#include <hip/hip_runtime.h>

#define NN 512
#define NB 128                 // 128 blocks x 4 anchors each
#define FMAGIC 0x5AD0F1A6u

// ---------------- single kernel: per-block srow dots + rows + atomic tail ----
// 128 blocks x 512 threads, 4 anchors per block (i = 4b..4b+3).
// Dot phase: each 16-lane group owns one row k per batch (coalesced 4x256B
// per wave instr); the loaded row feeds FOUR register-resident anchor chains
// (16 FMA per float4 load -> half the L2 traffic of the 256-block version).
// Grid-wide data flow is only the final 512-float sum, via RELAXED agent-scope
// atomics (coherence-point ops, no L2 writeback/invalidate storm).
__global__ __launch_bounds__(512) void sap_fused(const float* __restrict__ P,
                                                 const int* __restrict__ labels,
                                                 unsigned* __restrict__ pa_bits,
                                                 unsigned* __restrict__ flags,
                                                 float* __restrict__ out) {
    __shared__ float srow[4][NN];
    __shared__ int   labels_sh[NN];
    __shared__ float posf[NN];
    __shared__ int   poslist[NN];
    __shared__ int   npos_cnt;
    __shared__ float wave_part[8];
    __shared__ float pa_out[4];
    __shared__ float sh[256];

    const int t    = threadIdx.x;          // 0..511
    const int lane = t & 63;
    const int wave = t >> 6;               // 0..7
    const int g    = lane & 15;            // lane within 16-group
    const int grp  = lane >> 4;            // 0..3: row-group within wave
    const int b    = blockIdx.x;
    const int i0   = b * 4;

    if (t < 128) ((int4*)labels_sh)[t] = ((const int4*)labels)[t];

    // ---- 4 anchor rows into registers: lane's slots are float4 indices {g+16c}
    float4 a0[8], a1[8], a2[8], a3[8];
    {
        const float4* A0 = (const float4*)&P[(i0 + 0) * NN];
        const float4* A1 = (const float4*)&P[(i0 + 1) * NN];
        const float4* A2 = (const float4*)&P[(i0 + 2) * NN];
        const float4* A3 = (const float4*)&P[(i0 + 3) * NN];
#pragma unroll
        for (int c = 0; c < 8; ++c) {
            a0[c] = A0[g + 16 * c];
            a1[c] = A1[g + 16 * c];
            a2[c] = A2[g + 16 * c];
            a3[c] = A3[g + 16 * c];
        }
    }

    // ---- dot phase: wave w owns rows [64w, 64w+64); 4 rows in flight per batch
#pragma unroll 2
    for (int bb_ = 0; bb_ < 16; ++bb_) {
        const int k = wave * 64 + bb_ * 4 + grp;
        const float4* B = (const float4*)&P[k * NN];
        float4 bb[8];
#pragma unroll
        for (int c = 0; c < 8; ++c) bb[c] = B[g + 16 * c];
        float s0 = 0.f, s1 = 0.f, s2 = 0.f, s3 = 0.f;
#pragma unroll
        for (int c = 0; c < 8; ++c) {
            s0 += a0[c].x * bb[c].x; s0 += a0[c].y * bb[c].y;
            s0 += a0[c].z * bb[c].z; s0 += a0[c].w * bb[c].w;
            s1 += a1[c].x * bb[c].x; s1 += a1[c].y * bb[c].y;
            s1 += a1[c].z * bb[c].z; s1 += a1[c].w * bb[c].w;
            s2 += a2[c].x * bb[c].x; s2 += a2[c].y * bb[c].y;
            s2 += a2[c].z * bb[c].z; s2 += a2[c].w * bb[c].w;
            s3 += a3[c].x * bb[c].x; s3 += a3[c].y * bb[c].y;
            s3 += a3[c].z * bb[c].z; s3 += a3[c].w * bb[c].w;
        }
#pragma unroll
        for (int off = 1; off < 16; off <<= 1) {   // stays within the 16-group
            s0 += __shfl_xor(s0, off);
            s1 += __shfl_xor(s1, off);
            s2 += __shfl_xor(s2, off);
            s3 += __shfl_xor(s3, off);
        }
        if (g == 0) {
            srow[0][k] = s0; srow[1][k] = s1;
            srow[2][k] = s2; srow[3][k] = s3;
        }
    }

    // ---- rows phase (verbatim structure from verified rounds; 4 anchors now)
    const float C1   = 100.0f * 1.44269504088896340736f;
    const float CLIP = 50.0f  * 1.44269504088896340736f;

    for (int a = 0; a < 4; ++a) {
        const int i = i0 + a;
        __syncthreads();                   // srow ready / protect reused buffers
        if (t == 0) npos_cnt = 0;
        if (t < 8) wave_part[t] = 0.f;
        __syncthreads();
        const int li = labels_sh[i];
        {
            bool p  = (labels_sh[t] == li) && (t != i);
            posf[t] = p ? 1.f : 0.f;
            if (p) { int idx = atomicAdd(&npos_cnt, 1); poslist[idx] = t; }
        }
        __syncthreads();

        const int cnt = npos_cnt;          // positives excluding self
        if (cnt == 0) {                    // n_pos == 1 -> per_anchor = 0
            if (t == 0) pa_out[a] = 0.f;
            continue;
        }

        const float* sr = srow[a];
        float acc = 0.f;                   // lane-0 accumulation per wave
        for (int idx = wave; idx <= cnt; idx += 8) {   // idx==cnt -> j==i (eye)
            const int   j   = (idx == cnt) ? i : poslist[idx];
            const float sij = sr[j];
            float sum_all = 0.f, sum_pos = 0.f;
#pragma unroll
            for (int kk = 0; kk < 8; kk++) {
                const int k = lane + (kk << 6);
                float y = (sij - sr[k]) * C1;
                y = fminf(fmaxf(y, -CLIP), CLIP);
                float tt = 1.0f / (1.0f + exp2f(y));
                if (k == j) tt = 0.f;      // (1-eye)[j,k] factor
                sum_all += tt;
                sum_pos += tt * posf[k];   // posf[i]==0 excludes k==i
            }
#pragma unroll
            for (int off = 32; off; off >>= 1) {
                sum_all += __shfl_down(sum_all, off);
                sum_pos += __shfl_down(sum_pos, off);
            }
            if (lane == 0) {
                const float den = 1.0f + sum_all;
                acc += ((j == i) ? 1.0f : (1.0f + sum_pos)) / den;
            }
        }
        if (lane == 0) wave_part[wave] = acc;
        __syncthreads();
        if (t == 0) {
            float tot = 0.f;
#pragma unroll
            for (int w = 0; w < 8; ++w) tot += wave_part[w];
            pa_out[a] = tot / (float)(cnt + 1);
        }
    }
    __syncthreads();

    // ---- publish this block's four per_anchor values + flag (relaxed atomics)
    if (t == 0) {
#pragma unroll
        for (int a = 0; a < 4; ++a)
            __hip_atomic_store(&pa_bits[i0 + a], __float_as_uint(pa_out[a]),
                               __ATOMIC_RELAXED, __HIP_MEMORY_SCOPE_AGENT);
        // order data-atomics before flag-atomic without any cache writeback:
        asm volatile("s_waitcnt vmcnt(0)" ::: "memory");
        __hip_atomic_store(&flags[b], FMAGIC,
                           __ATOMIC_RELAXED, __HIP_MEMORY_SCOPE_AGENT);
    }

    if (b != 0) return;                    // finisher is block 0

    // ---- block 0: wait for all flags (relaxed polls -> no L2 inv storm)
    if (t < NB) {
        while (__hip_atomic_load(&flags[t], __ATOMIC_RELAXED,
                                 __HIP_MEMORY_SCOPE_AGENT) != FMAGIC)
            __builtin_amdgcn_s_sleep(8);
        // reset for replay-robustness (0 != FMAGIC)
        __hip_atomic_store(&flags[t], 0u, __ATOMIC_RELAXED,
                           __HIP_MEMORY_SCOPE_AGENT);
    }
    __syncthreads();

    // ---- final reduce (bitwise-identical round-0 tree)
    if (t < 256) {
        float v0 = __uint_as_float(__hip_atomic_load(&pa_bits[t], __ATOMIC_RELAXED,
                                                     __HIP_MEMORY_SCOPE_AGENT));
        float v1 = __uint_as_float(__hip_atomic_load(&pa_bits[t + 256], __ATOMIC_RELAXED,
                                                     __HIP_MEMORY_SCOPE_AGENT));
        sh[t] = v0 + v1;
    }
    __syncthreads();
    for (int s = 128; s; s >>= 1) {
        if (t < s) sh[t] += sh[t + s];
        __syncthreads();
    }
    if (t == 0) out[0] = 1.0f - sh[0] / (float)NN;
}

extern "C" void kernel_launch(void* const* d_in, const int* in_sizes, int n_in,
                              void* d_out, int out_size, void* d_ws, size_t ws_size,
                              hipStream_t stream) {
    const float* preds  = (const float*)d_in[0];
    const int*   labels = (const int*)d_in[1];
    float* out = (float*)d_out;

    unsigned* pa_bits = (unsigned*)d_ws;           // 512 u32 (float bits)
    unsigned* flags   = pa_bits + NN;              // 128 u32

    sap_fused<<<NB, 512, 0, stream>>>(preds, labels, pa_bits, flags, out);
}

// Round 6
// 72.230 us; speedup vs baseline: 1.1318x; 1.1318x over previous
//
#include <hip/hip_runtime.h>

#define NN 512
#define NB 256                 // 256 blocks x 2 anchors each
#define NT 1024                // 16 waves/block -> 4 waves/SIMD (latency hiding)
#define FMAGIC 0x5AD0F1A6u

// ---------------- single kernel: per-block srow dots + rows + atomic tail ----
// 256 blocks x 1024 threads, 2 anchors per block (i = 2b, 2b+1).
// Round-5 lesson: dot phase is LATENCY-bound, not L2-BW-bound -> keep 256
// blocks (full CU coverage, 256 MB aggregate L2 traffic) and double waves/SIMD
// (2 -> 4) instead of shrinking the grid. Per-row dot order (16-lane groups,
// slots g+16c, xor tree 1/2/4/8) is bitwise-identical to rounds 2/4.
// Grid-wide data flow remains only the final 512-float sum via RELAXED
// agent-scope atomics (no L2 writeback/invalidate storm -- round-3 lesson).
__global__ __launch_bounds__(NT, 4) void sap_fused(const float* __restrict__ P,
                                                   const int* __restrict__ labels,
                                                   unsigned* __restrict__ pa_bits,
                                                   unsigned* __restrict__ flags,
                                                   float* __restrict__ out) {
    __shared__ float srow[2][NN];
    __shared__ int   labels_sh[NN];
    __shared__ float posf[NN];
    __shared__ int   poslist[NN];
    __shared__ int   npos_cnt;
    __shared__ float wave_part[16];
    __shared__ float pa_out[2];
    __shared__ float sh[256];

    const int t    = threadIdx.x;          // 0..1023
    const int lane = t & 63;
    const int wave = t >> 6;               // 0..15
    const int g    = lane & 15;            // lane within 16-group
    const int grp  = lane >> 4;            // 0..3: row-group within wave
    const int b    = blockIdx.x;
    const int i0   = b * 2;

    if (t < 128) ((int4*)labels_sh)[t] = ((const int4*)labels)[t];

    // ---- anchor rows into registers: lane's slots are float4 indices {g+16c}
    float4 a0[8], a1[8];
    {
        const float4* A0 = (const float4*)&P[i0 * NN];
        const float4* A1 = (const float4*)&P[(i0 + 1) * NN];
#pragma unroll
        for (int c = 0; c < 8; ++c) {
            a0[c] = A0[g + 16 * c];
            a1[c] = A1[g + 16 * c];
        }
    }

    // ---- dot phase: wave w owns rows [32w, 32w+32); 4 rows in flight per batch
#pragma unroll 2
    for (int bb_ = 0; bb_ < 8; ++bb_) {
        const int k = wave * 32 + bb_ * 4 + grp;
        const float4* B = (const float4*)&P[k * NN];
        float s0 = 0.f, s1 = 0.f;
#pragma unroll
        for (int c = 0; c < 8; ++c) {
            const float4 bb = B[g + 16 * c];
            s0 += a0[c].x * bb.x; s0 += a0[c].y * bb.y;
            s0 += a0[c].z * bb.z; s0 += a0[c].w * bb.w;
            s1 += a1[c].x * bb.x; s1 += a1[c].y * bb.y;
            s1 += a1[c].z * bb.z; s1 += a1[c].w * bb.w;
        }
#pragma unroll
        for (int off = 1; off < 16; off <<= 1) {   // stays within the 16-group
            s0 += __shfl_xor(s0, off);
            s1 += __shfl_xor(s1, off);
        }
        if (g == 0) { srow[0][k] = s0; srow[1][k] = s1; }
    }

    // ---- rows phase (same per-j math as all verified rounds; 16 waves now)
    const float C1   = 100.0f * 1.44269504088896340736f;
    const float CLIP = 50.0f  * 1.44269504088896340736f;

    for (int a = 0; a < 2; ++a) {
        const int i = i0 + a;
        __syncthreads();                   // srow ready / protect reused buffers
        if (t == 0) npos_cnt = 0;
        if (t < 16) wave_part[t] = 0.f;
        __syncthreads();
        const int li = labels_sh[i];
        if (t < NN) {
            bool p  = (labels_sh[t] == li) && (t != i);
            posf[t] = p ? 1.f : 0.f;
            if (p) { int idx = atomicAdd(&npos_cnt, 1); poslist[idx] = t; }
        }
        __syncthreads();

        const int cnt = npos_cnt;          // positives excluding self
        if (cnt == 0) {                    // n_pos == 1 -> per_anchor = 0
            if (t == 0) pa_out[a] = 0.f;
            continue;
        }

        const float* sr = srow[a];
        float acc = 0.f;                   // lane-0 accumulation per wave
        for (int idx = wave; idx <= cnt; idx += 16) {  // idx==cnt -> j==i (eye)
            const int   j   = (idx == cnt) ? i : poslist[idx];
            const float sij = sr[j];
            float sum_all = 0.f, sum_pos = 0.f;
#pragma unroll
            for (int kk = 0; kk < 8; kk++) {
                const int k = lane + (kk << 6);
                float y = (sij - sr[k]) * C1;
                y = fminf(fmaxf(y, -CLIP), CLIP);
                float tt = 1.0f / (1.0f + exp2f(y));
                if (k == j) tt = 0.f;      // (1-eye)[j,k] factor
                sum_all += tt;
                sum_pos += tt * posf[k];   // posf[i]==0 excludes k==i
            }
#pragma unroll
            for (int off = 32; off; off >>= 1) {
                sum_all += __shfl_down(sum_all, off);
                sum_pos += __shfl_down(sum_pos, off);
            }
            if (lane == 0) {
                const float den = 1.0f + sum_all;
                acc += ((j == i) ? 1.0f : (1.0f + sum_pos)) / den;
            }
        }
        if (lane == 0) wave_part[wave] = acc;
        __syncthreads();
        if (t == 0) {
            float tot = 0.f;
#pragma unroll
            for (int w = 0; w < 16; ++w) tot += wave_part[w];
            pa_out[a] = tot / (float)(cnt + 1);
        }
    }
    __syncthreads();

    // ---- publish this block's two per_anchor values + flag (relaxed atomics)
    if (t == 0) {
        __hip_atomic_store(&pa_bits[i0],     __float_as_uint(pa_out[0]),
                           __ATOMIC_RELAXED, __HIP_MEMORY_SCOPE_AGENT);
        __hip_atomic_store(&pa_bits[i0 + 1], __float_as_uint(pa_out[1]),
                           __ATOMIC_RELAXED, __HIP_MEMORY_SCOPE_AGENT);
        // order data-atomics before flag-atomic without any cache writeback:
        asm volatile("s_waitcnt vmcnt(0)" ::: "memory");
        __hip_atomic_store(&flags[b], FMAGIC,
                           __ATOMIC_RELAXED, __HIP_MEMORY_SCOPE_AGENT);
    }

    if (b != 0) return;                    // finisher is block 0

    // ---- block 0: wait for all flags (relaxed polls -> no L2 inv storm)
    if (t < NB) {
        while (__hip_atomic_load(&flags[t], __ATOMIC_RELAXED,
                                 __HIP_MEMORY_SCOPE_AGENT) != FMAGIC)
            __builtin_amdgcn_s_sleep(8);
        // reset for replay-robustness (0 != FMAGIC)
        __hip_atomic_store(&flags[t], 0u, __ATOMIC_RELAXED,
                           __HIP_MEMORY_SCOPE_AGENT);
    }
    __syncthreads();

    // ---- final reduce (bitwise-identical round-0 tree)
    if (t < 256) {
        float v0 = __uint_as_float(__hip_atomic_load(&pa_bits[t], __ATOMIC_RELAXED,
                                                     __HIP_MEMORY_SCOPE_AGENT));
        float v1 = __uint_as_float(__hip_atomic_load(&pa_bits[t + 256], __ATOMIC_RELAXED,
                                                     __HIP_MEMORY_SCOPE_AGENT));
        sh[t] = v0 + v1;
    }
    __syncthreads();
    for (int s = 128; s; s >>= 1) {
        if (t < s) sh[t] += sh[t + s];
        __syncthreads();
    }
    if (t == 0) out[0] = 1.0f - sh[0] / (float)NN;
}

extern "C" void kernel_launch(void* const* d_in, const int* in_sizes, int n_in,
                              void* d_out, int out_size, void* d_ws, size_t ws_size,
                              hipStream_t stream) {
    const float* preds  = (const float*)d_in[0];
    const int*   labels = (const int*)d_in[1];
    float* out = (float*)d_out;

    unsigned* pa_bits = (unsigned*)d_ws;           // 512 u32 (float bits)
    unsigned* flags   = pa_bits + NN;              // 256 u32

    sap_fused<<<NB, NT, 0, stream>>>(preds, labels, pa_bits, flags, out);
}